// Round 1
// baseline (417.012 us; speedup 1.0000x reference)
//
#include <hip/hip_runtime.h>
#include <hip/hip_bf16.h>

// PerSquareInputEncoder: out[b,s,:] = (sum_h W_board[h*13+board[b,h,s]]
//   + ep[b,s]*W_board[104] + meta[b]@W_meta + square_emb[s]) * square_scale[s]
//   + square_bias[s] + tc_table[tc_cat[b]]
// B=4096, H=8, P=13, D=256. Output (B,64,256) fp32 = 268 MB -> HBM-write-bound.

#define D 256
#define HD 8
#define PD 13

__global__ __launch_bounds__(256) void encoder_kernel(
    const int*   __restrict__ board,   // (B,8,64) int32
    const float* __restrict__ time_h,  // (B,8)
    const float* __restrict__ rep,     // (B,8)
    const float* __restrict__ castl,   // (B,4)
    const float* __restrict__ ep,      // (B,64)
    const float* __restrict__ scal,    // (B,8)
    const int*   __restrict__ tc_cat,  // (B)
    const float* __restrict__ Wb,      // (105,256)
    const float* __restrict__ Wm,      // (28,256)
    const float* __restrict__ emb,     // (64,256)
    const float* __restrict__ sscale,  // (64,256)
    const float* __restrict__ sbias,   // (64,256)
    const float* __restrict__ tc_tab,  // (8,256)
    float*       __restrict__ out)     // (B,64,256)
{
    const int b   = blockIdx.x;
    const int tid = threadIdx.x;          // 0..255

    __shared__ float s_meta[28];
    __shared__ float s_mv[D];             // meta @ W_meta
    __shared__ float s_tc[D];
    __shared__ int   s_board[HD * 64];    // 512 ints
    __shared__ float s_ep[64];

    // stage meta features: [time(8), rep(8), castling(4), scalars(8)]
    if (tid < 8)        s_meta[tid]      = time_h[b * 8 + tid];
    else if (tid < 16)  s_meta[tid]      = rep[b * 8 + (tid - 8)];
    else if (tid < 20)  s_meta[tid]      = castl[b * 4 + (tid - 16)];
    else if (tid < 28)  s_meta[tid]      = scal[b * 8 + (tid - 20)];

    // stage board history (512 ints, 2 per thread) and ep mask
    s_board[tid]       = board[b * 512 + tid];
    s_board[tid + 256] = board[b * 512 + 256 + tid];
    if (tid < 64) s_ep[tid] = ep[b * 64 + tid];

    // tc row
    const int tcc = tc_cat[b];
    s_tc[tid] = tc_tab[tcc * D + tid];
    __syncthreads();

    // meta_vec[d] = sum_f meta[f] * W_meta[f,d]   (coalesced Wm reads)
    float mv = 0.0f;
    #pragma unroll
    for (int f = 0; f < 28; ++f)
        mv = fmaf(s_meta[f], Wm[f * D + tid], mv);
    s_mv[tid] = mv;
    __syncthreads();

    const int wave = tid >> 6;   // 0..3: square group
    const int lane = tid & 63;   // d/4 index
    const int d    = lane * 4;

    // per-lane invariants across squares
    const float4 mv4  = *(const float4*)(&s_mv[d]);
    const float4 tc4  = *(const float4*)(&s_tc[d]);
    const float4 w104 = *(const float4*)(&Wb[104 * D + d]);

    for (int s = wave; s < 64; s += 4) {
        float4 acc = mv4;
        // 8 one-hot gathers: all 64 lanes share the row -> coalesced 1KB read
        #pragma unroll
        for (int h = 0; h < HD; ++h) {
            const int p = s_board[h * 64 + s];           // LDS broadcast
            const float4 w = *(const float4*)(&Wb[(h * PD + p) * D + d]);
            acc.x += w.x; acc.y += w.y; acc.z += w.z; acc.w += w.w;
        }
        const float epv = s_ep[s];
        acc.x = fmaf(epv, w104.x, acc.x);
        acc.y = fmaf(epv, w104.y, acc.y);
        acc.z = fmaf(epv, w104.z, acc.z);
        acc.w = fmaf(epv, w104.w, acc.w);

        const float4 e  = *(const float4*)(&emb[s * D + d]);
        const float4 sc = *(const float4*)(&sscale[s * D + d]);
        const float4 bi = *(const float4*)(&sbias[s * D + d]);

        float4 x;
        x.x = fmaf(acc.x + e.x, sc.x, bi.x) + tc4.x;
        x.y = fmaf(acc.y + e.y, sc.y, bi.y) + tc4.y;
        x.z = fmaf(acc.z + e.z, sc.z, bi.z) + tc4.z;
        x.w = fmaf(acc.w + e.w, sc.w, bi.w) + tc4.w;

        *(float4*)(&out[(size_t)b * 64 * D + s * D + d]) = x;
    }
}

extern "C" void kernel_launch(void* const* d_in, const int* in_sizes, int n_in,
                              void* d_out, int out_size, void* d_ws, size_t ws_size,
                              hipStream_t stream) {
    const int*   board  = (const int*)  d_in[0];
    const float* time_h = (const float*)d_in[1];
    const float* rep    = (const float*)d_in[2];
    const float* castl  = (const float*)d_in[3];
    const float* ep     = (const float*)d_in[4];
    const float* scal   = (const float*)d_in[5];
    const int*   tc_cat = (const int*)  d_in[6];
    const float* Wb     = (const float*)d_in[7];
    const float* Wm     = (const float*)d_in[8];
    const float* emb    = (const float*)d_in[9];
    const float* sscale = (const float*)d_in[10];
    const float* sbias  = (const float*)d_in[11];
    const float* tc_tab = (const float*)d_in[12];
    float* out = (float*)d_out;

    const int B = in_sizes[6];   // tc_cat has one entry per batch row
    encoder_kernel<<<B, 256, 0, stream>>>(board, time_h, rep, castl, ep, scal,
                                          tc_cat, Wb, Wm, emb, sscale, sbias,
                                          tc_tab, out);
}

// Round 2
// 370.879 us; speedup vs baseline: 1.1244x; 1.1244x over previous
//
#include <hip/hip_runtime.h>
#include <hip/hip_bf16.h>

// PerSquareInputEncoder: out[b,s,:] = (sum_h W_board[h*13+board[b,h,s]]
//   + ep[b,s]*W_board[104] + meta[b]@W_meta + square_emb[s]) * square_scale[s]
//   + square_bias[s] + tc_table[tc_cat[b]]
// B=4096, H=8, P=13, D=256. Output (B,64,256) fp32 = 268 MB -> HBM-write-bound
// roofline ~42 us. R1 was 183 us: latency-bound on L2 row gathers (8 KB read
// from L2 per 1 KB written). Fix: stage W_board in LDS as bf16 (53.8 KB ->
// 2 blocks/CU), gather via ds_read_b64; 8 batch rows per block amortize staging.

#define D 256
#define HD 8
#define PD 13
#define NB 8            // batch rows per block
#define WB_ROWS 105
#define WB_ELEMS (WB_ROWS * D)      // 26880 bf16
#define WB_F4    (WB_ELEMS / 4)     // 6720 float4 groups

__device__ __forceinline__ unsigned short f2bf(float f) {
    unsigned int u = __float_as_uint(f);
    unsigned int r = (u + 0x7fffu + ((u >> 16) & 1u)) >> 16;   // RNE
    return (unsigned short)r;
}
__device__ __forceinline__ float bf_lo(unsigned int u) { return __uint_as_float(u << 16); }
__device__ __forceinline__ float bf_hi(unsigned int u) { return __uint_as_float(u & 0xffff0000u); }

__global__ __launch_bounds__(256) void encoder_kernel(
    const int*   __restrict__ board,   // (B,8,64) int32
    const float* __restrict__ time_h,  // (B,8)
    const float* __restrict__ rep,     // (B,8)
    const float* __restrict__ castl,   // (B,4)
    const float* __restrict__ ep,      // (B,64)
    const float* __restrict__ scal,    // (B,8)
    const int*   __restrict__ tc_cat,  // (B)
    const float* __restrict__ Wb,      // (105,256) fp32
    const float* __restrict__ Wm,      // (28,256)
    const float* __restrict__ emb,     // (64,256)
    const float* __restrict__ sscale,  // (64,256)
    const float* __restrict__ sbias,   // (64,256)
    const float* __restrict__ tc_tab,  // (8,256)
    float*       __restrict__ out,     // (B,64,256)
    int Btot)
{
    __shared__ __align__(16) unsigned short sWb[WB_ELEMS]; // 53760 B, bf16 W_board
    __shared__ int   s_off[HD * 64];   // precomputed row byte offsets into sWb
    __shared__ float s_ep[64];
    __shared__ float s_meta[28];

    const int tid  = threadIdx.x;
    const int wave = tid >> 6;
    const int lane = tid & 63;
    const int d    = lane * 4;

    // ---- one-time: stage W_board as bf16 into LDS (fp32 float4 -> packed uint2)
    for (int i = tid; i < WB_F4; i += 256) {
        const float4 w = *(const float4*)(Wb + i * 4);
        uint2 pk;
        pk.x = (unsigned int)f2bf(w.x) | ((unsigned int)f2bf(w.y) << 16);
        pk.y = (unsigned int)f2bf(w.z) | ((unsigned int)f2bf(w.w) << 16);
        *(uint2*)(&sWb[i * 4]) = pk;
    }

    // per-lane invariants (fp32 ep row, kept exact)
    const float4 w104 = *(const float4*)(&Wb[104 * D + d]);

    const int b0 = blockIdx.x * NB;
    const int nb = min(NB, Btot - b0);

    for (int bi = 0; bi < nb; ++bi) {
        const int b = b0 + bi;

        __syncthreads();   // previous iter done with s_off/s_ep/s_meta; Wb staged (iter 0)

        // ---- stage per-b: row byte-offsets, ep, meta
        {
            int e = tid;
            #pragma unroll
            for (int r = 0; r < 2; ++r, e += 256) {
                const int p = board[b * 512 + e];
                s_off[e] = ((e >> 6) * PD + p) * (D * 2);   // byte offset of bf16 row
            }
        }
        if (tid < 64) s_ep[tid] = ep[b * 64 + tid];
        if (tid < 8)        s_meta[tid] = time_h[b * 8 + tid];
        else if (tid < 16)  s_meta[tid] = rep[b * 8 + (tid - 8)];
        else if (tid < 20)  s_meta[tid] = castl[b * 4 + (tid - 16)];
        else if (tid < 28)  s_meta[tid] = scal[b * 8 + (tid - 20)];

        __syncthreads();

        // ---- per-wave meta projection (Wm rows L1/L2-resident)
        float4 mv = make_float4(0.f, 0.f, 0.f, 0.f);
        #pragma unroll
        for (int f = 0; f < 28; ++f) {
            const float  m = s_meta[f];
            const float4 w = *(const float4*)(&Wm[f * D + d]);
            mv.x = fmaf(m, w.x, mv.x);
            mv.y = fmaf(m, w.y, mv.y);
            mv.z = fmaf(m, w.z, mv.z);
            mv.w = fmaf(m, w.w, mv.w);
        }
        const int tcc = tc_cat[b];
        const float4 tc4 = *(const float4*)(&tc_tab[tcc * D + d]);

        const size_t outb = (size_t)b * 64 * D;
        const char* wb_base = (const char*)sWb + (size_t)lane * 8;

        // ---- 16 squares per wave
        #pragma unroll 4
        for (int i = 0; i < 16; ++i) {
            const int s = wave * 16 + i;
            float4 acc = mv;
            #pragma unroll
            for (int h = 0; h < HD; ++h) {
                const int ro = s_off[h * 64 + s];          // LDS broadcast
                const uint2 u = *(const uint2*)(wb_base + ro);
                acc.x += bf_lo(u.x);
                acc.y += bf_hi(u.x);
                acc.z += bf_lo(u.y);
                acc.w += bf_hi(u.y);
            }
            const float epv = s_ep[s];
            acc.x = fmaf(epv, w104.x, acc.x);
            acc.y = fmaf(epv, w104.y, acc.y);
            acc.z = fmaf(epv, w104.z, acc.z);
            acc.w = fmaf(epv, w104.w, acc.w);

            const float4 e  = *(const float4*)(&emb[s * D + d]);
            const float4 sc = *(const float4*)(&sscale[s * D + d]);
            const float4 bi4 = *(const float4*)(&sbias[s * D + d]);

            float4 x;
            x.x = fmaf(acc.x + e.x, sc.x, bi4.x) + tc4.x;
            x.y = fmaf(acc.y + e.y, sc.y, bi4.y) + tc4.y;
            x.z = fmaf(acc.z + e.z, sc.z, bi4.z) + tc4.z;
            x.w = fmaf(acc.w + e.w, sc.w, bi4.w) + tc4.w;

            *(float4*)(&out[outb + s * D + d]) = x;
        }
    }
}

extern "C" void kernel_launch(void* const* d_in, const int* in_sizes, int n_in,
                              void* d_out, int out_size, void* d_ws, size_t ws_size,
                              hipStream_t stream) {
    const int*   board  = (const int*)  d_in[0];
    const float* time_h = (const float*)d_in[1];
    const float* rep    = (const float*)d_in[2];
    const float* castl  = (const float*)d_in[3];
    const float* ep     = (const float*)d_in[4];
    const float* scal   = (const float*)d_in[5];
    const int*   tc_cat = (const int*)  d_in[6];
    const float* Wb     = (const float*)d_in[7];
    const float* Wm     = (const float*)d_in[8];
    const float* emb    = (const float*)d_in[9];
    const float* sscale = (const float*)d_in[10];
    const float* sbias  = (const float*)d_in[11];
    const float* tc_tab = (const float*)d_in[12];
    float* out = (float*)d_out;

    const int B = in_sizes[6];
    const int grid = (B + NB - 1) / NB;
    encoder_kernel<<<grid, 256, 0, stream>>>(board, time_h, rep, castl, ep, scal,
                                             tc_cat, Wb, Wm, emb, sscale, sbias,
                                             tc_tab, out, B);
}

// Round 3
// 350.157 us; speedup vs baseline: 1.1909x; 1.0592x over previous
//
#include <hip/hip_runtime.h>
#include <hip/hip_bf16.h>

// PerSquareInputEncoder: out[b,s,:] = (sum_h W_board[h*13+board[b,h,s]]
//   + ep[b,s]*W_board[104] + meta[b]@W_meta + square_emb[s]) * square_scale[s]
//   + square_bias[s] + tc_table[tc_cat[b]]
// B=4096, H=8, P=13, D=256. Output 268 MB fp32 -> write roofline ~42 us.
// R2 (137 us) was barrier-drain-bound: per-row __syncthreads forced vmcnt(0)
// store drains. R3: stage bf16 W_board in LDS ONCE (one sync), then waves are
// fully independent (board idx via register __shfl/readlane broadcast, meta via
// wave-uniform scalar loads) -> stores pipeline, no barriers in steady state.

#define D 256
#define HD 8
#define PD 13
#define ROWS_PER_WAVE 2
#define ROWS_PER_BLOCK 8     // 4 waves * 2 rows
#define WB_ROWS 105
#define WB_ELEMS (WB_ROWS * D)      // 26880 bf16 = 53760 B LDS (2 blocks/CU)
#define WB_F4    (WB_ELEMS / 4)

__device__ __forceinline__ unsigned short f2bf(float f) {
    unsigned int u = __float_as_uint(f);
    return (unsigned short)((u + 0x7fffu + ((u >> 16) & 1u)) >> 16);  // RNE
}
__device__ __forceinline__ float bf_lo(unsigned int u) { return __uint_as_float(u << 16); }
__device__ __forceinline__ float bf_hi(unsigned int u) { return __uint_as_float(u & 0xffff0000u); }

__global__ __launch_bounds__(256) void encoder_kernel(
    const int*   __restrict__ board,   // (B,8,64) int32
    const float* __restrict__ time_h,  // (B,8)
    const float* __restrict__ rep,     // (B,8)
    const float* __restrict__ castl,   // (B,4)
    const float* __restrict__ ep,      // (B,64)
    const float* __restrict__ scal,    // (B,8)
    const int*   __restrict__ tc_cat,  // (B)
    const float* __restrict__ Wb,      // (105,256) fp32
    const float* __restrict__ Wm,      // (28,256)
    const float* __restrict__ emb,     // (64,256)
    const float* __restrict__ sscale,  // (64,256)
    const float* __restrict__ sbias,   // (64,256)
    const float* __restrict__ tc_tab,  // (8,256)
    float*       __restrict__ out,     // (B,64,256)
    int Btot)
{
    __shared__ __align__(16) unsigned short sWb[WB_ELEMS];

    const int tid  = threadIdx.x;
    const int wave = tid >> 6;
    const int lane = tid & 63;
    const int d    = lane * 4;

    // ---- one-time: stage W_board as bf16 into LDS
    for (int i = tid; i < WB_F4; i += 256) {
        const float4 w = *(const float4*)(Wb + i * 4);
        uint2 pk;
        pk.x = (unsigned int)f2bf(w.x) | ((unsigned int)f2bf(w.y) << 16);
        pk.y = (unsigned int)f2bf(w.z) | ((unsigned int)f2bf(w.w) << 16);
        *(uint2*)(&sWb[i * 4]) = pk;
    }

    const float4 w104 = *(const float4*)(&Wb[104 * D + d]);

    __syncthreads();   // the ONLY barrier

    // ---- per-wave row setup (2 rows, fully independent from here on)
    const int b_base = blockIdx.x * ROWS_PER_BLOCK + wave * ROWS_PER_WAVE;

    int    bh[ROWS_PER_WAVE][HD];   // lane = square: board[b][h][lane]
    float  epr[ROWS_PER_WAVE];
    float4 mv[ROWS_PER_WAVE];
    float4 tc[ROWS_PER_WAVE];
    bool   valid[ROWS_PER_WAVE];

    #pragma unroll
    for (int r = 0; r < ROWS_PER_WAVE; ++r) {
        const int b = b_base + r;
        valid[r] = (b < Btot);
        const int bc = valid[r] ? b : 0;

        #pragma unroll
        for (int h = 0; h < HD; ++h)
            bh[r][h] = board[bc * 512 + h * 64 + lane];
        epr[r] = ep[bc * 64 + lane];

        // meta projection: 28 wave-uniform scalars x Wm rows (L1-resident)
        float4 m = make_float4(0.f, 0.f, 0.f, 0.f);
        #pragma unroll
        for (int f = 0; f < 8; ++f) {
            const float  c = time_h[bc * 8 + f];
            const float4 w = *(const float4*)(&Wm[f * D + d]);
            m.x = fmaf(c, w.x, m.x); m.y = fmaf(c, w.y, m.y);
            m.z = fmaf(c, w.z, m.z); m.w = fmaf(c, w.w, m.w);
        }
        #pragma unroll
        for (int f = 0; f < 8; ++f) {
            const float  c = rep[bc * 8 + f];
            const float4 w = *(const float4*)(&Wm[(8 + f) * D + d]);
            m.x = fmaf(c, w.x, m.x); m.y = fmaf(c, w.y, m.y);
            m.z = fmaf(c, w.z, m.z); m.w = fmaf(c, w.w, m.w);
        }
        #pragma unroll
        for (int f = 0; f < 4; ++f) {
            const float  c = castl[bc * 4 + f];
            const float4 w = *(const float4*)(&Wm[(16 + f) * D + d]);
            m.x = fmaf(c, w.x, m.x); m.y = fmaf(c, w.y, m.y);
            m.z = fmaf(c, w.z, m.z); m.w = fmaf(c, w.w, m.w);
        }
        #pragma unroll
        for (int f = 0; f < 8; ++f) {
            const float  c = scal[bc * 8 + f];
            const float4 w = *(const float4*)(&Wm[(20 + f) * D + d]);
            m.x = fmaf(c, w.x, m.x); m.y = fmaf(c, w.y, m.y);
            m.z = fmaf(c, w.z, m.z); m.w = fmaf(c, w.w, m.w);
        }
        mv[r] = m;
        tc[r] = *(const float4*)(&tc_tab[tc_cat[bc] * D + d]);
    }

    const char* wb_lane = (const char*)sWb + (size_t)lane * 8;

    // ---- squares outer (emb/scale/bias loaded once, reused for both rows)
    #pragma unroll 2
    for (int s = 0; s < 64; ++s) {
        const float4 e  = *(const float4*)(&emb[s * D + d]);
        const float4 sc = *(const float4*)(&sscale[s * D + d]);
        const float4 bi = *(const float4*)(&sbias[s * D + d]);

        #pragma unroll
        for (int r = 0; r < ROWS_PER_WAVE; ++r) {
            if (!valid[r]) continue;
            float4 acc = mv[r];
            #pragma unroll
            for (int h = 0; h < HD; ++h) {
                const int p = __shfl(bh[r][h], s, 64);     // uniform -> readlane
                const uint2 u = *(const uint2*)(wb_lane + (h * PD + p) * (D * 2));
                acc.x += bf_lo(u.x);
                acc.y += bf_hi(u.x);
                acc.z += bf_lo(u.y);
                acc.w += bf_hi(u.y);
            }
            const float epv = __shfl(epr[r], s, 64);
            acc.x = fmaf(epv, w104.x, acc.x);
            acc.y = fmaf(epv, w104.y, acc.y);
            acc.z = fmaf(epv, w104.z, acc.z);
            acc.w = fmaf(epv, w104.w, acc.w);

            float4 x;
            x.x = fmaf(acc.x + e.x, sc.x, bi.x) + tc[r].x;
            x.y = fmaf(acc.y + e.y, sc.y, bi.y) + tc[r].y;
            x.z = fmaf(acc.z + e.z, sc.z, bi.z) + tc[r].z;
            x.w = fmaf(acc.w + e.w, sc.w, bi.w) + tc[r].w;

            *(float4*)(&out[(size_t)(b_base + r) * 64 * D + s * D + d]) = x;
        }
    }
}

extern "C" void kernel_launch(void* const* d_in, const int* in_sizes, int n_in,
                              void* d_out, int out_size, void* d_ws, size_t ws_size,
                              hipStream_t stream) {
    const int*   board  = (const int*)  d_in[0];
    const float* time_h = (const float*)d_in[1];
    const float* rep    = (const float*)d_in[2];
    const float* castl  = (const float*)d_in[3];
    const float* ep     = (const float*)d_in[4];
    const float* scal   = (const float*)d_in[5];
    const int*   tc_cat = (const int*)  d_in[6];
    const float* Wb     = (const float*)d_in[7];
    const float* Wm     = (const float*)d_in[8];
    const float* emb    = (const float*)d_in[9];
    const float* sscale = (const float*)d_in[10];
    const float* sbias  = (const float*)d_in[11];
    const float* tc_tab = (const float*)d_in[12];
    float* out = (float*)d_out;

    const int B = in_sizes[6];
    const int grid = (B + ROWS_PER_BLOCK - 1) / ROWS_PER_BLOCK;
    encoder_kernel<<<grid, 256, 0, stream>>>(board, time_h, rep, castl, ep, scal,
                                             tc_cat, Wb, Wm, emb, sscale, sbias,
                                             tc_tab, out, B);
}